// Round 4
// baseline (203.258 us; speedup 1.0000x reference)
//
#include <hip/hip_runtime.h>

// Fused Xcodec2 ISTFT: B=16, FREQ=513, FRAMES=2048, n_fft=1024, hop=256, win=1024
// out: [16, 1, 524288] fp32
//
// One-frame-per-wave version (barrier-free FFT), round 4:
//  - Spectra staged coalesced global -> frame-major LDS rows (float2 loads),
//    invalid frame-pairs zeroed at staging (validity is pair-aligned).
//  - Each wave runs one 512-pt complex inverse FFT (radix-8 Stockham, 3 reg
//    butterflies, 2 in-row LDS exchanges) in its own LDS row; wave-local
//    lgkmcnt fences only. Z slots XOR-swizzled (a = s ^ (s>>3)): conflict-free.
//  - ALL twiddles live in registers (1 sincos + 6 cmul chain per pass set),
//    removing the TW LDS table and its 4-way/8-way bank-conflicted reads.
//  - Windowed frame written with SWZ(x)=x^((x&32)>>1) bank swizzle; OLA reads
//    apply the same swizzle (aligned 32-runs stay bank-permutations).
//  - ifft scale (0.5/512) folded into the LDS window table.
//  - COLA: sum_j hann^2(p+256j) = 1.5 -> invenv = 2/3 except edges.
//  - 2 barriers total.

#define B_      16
#define FREQ_   513
#define FRAMES_ 2048
#define HOP_    256
#define NH_     512
#define PAD_    384
#define T_OUT_  524288
#define HPW     12           // useful hops per WG
#define SPW     3072         // output samples per WG
#define NCHUNK  171          // ceil(T_OUT/SPW)

#define FS2     515          // float2 stride of one frame row in S
#define PREOFF  8240         // float2 offset of PRE (16*515)
#define WINOFF  8752         // float2 offset of WIN
#define LDS2N   9264         // total float2 (74,112 B -> 2 WG/CU)

#define LGKM_SYNC() asm volatile("s_waitcnt lgkmcnt(0)" ::: "memory")
#define SWZ(x) ((x) ^ (((x) & 32) >> 1))

__device__ __forceinline__ float2 cmul(float2 a, float2 b) {
  return make_float2(a.x * b.x - a.y * b.y, a.x * b.y + a.y * b.x);
}

// 8-point inverse DFT (sign +i), DIF, in-place; output slot r holds y[brev3(r)].
__device__ __forceinline__ void idft8(float* zr, float* zi) {
  const float C = 0.70710678118654752f;
  float tr, ti;
  tr = zr[0]-zr[4]; ti = zi[0]-zi[4]; zr[0]+=zr[4]; zi[0]+=zi[4]; zr[4]=tr;         zi[4]=ti;
  tr = zr[1]-zr[5]; ti = zi[1]-zi[5]; zr[1]+=zr[5]; zi[1]+=zi[5]; zr[5]=C*(tr-ti);  zi[5]=C*(tr+ti);
  tr = zr[2]-zr[6]; ti = zi[2]-zi[6]; zr[2]+=zr[6]; zi[2]+=zi[6]; zr[6]=-ti;        zi[6]=tr;
  tr = zr[3]-zr[7]; ti = zi[3]-zi[7]; zr[3]+=zr[7]; zi[3]+=zi[7]; zr[7]=-C*(tr+ti); zi[7]=C*(tr-ti);
  tr = zr[0]-zr[2]; ti = zi[0]-zi[2]; zr[0]+=zr[2]; zi[0]+=zi[2]; zr[2]=tr;  zi[2]=ti;
  tr = zr[1]-zr[3]; ti = zi[1]-zi[3]; zr[1]+=zr[3]; zi[1]+=zi[3]; zr[3]=-ti; zi[3]=tr;
  tr = zr[4]-zr[6]; ti = zi[4]-zi[6]; zr[4]+=zr[6]; zi[4]+=zi[6]; zr[6]=tr;  zi[6]=ti;
  tr = zr[5]-zr[7]; ti = zi[5]-zi[7]; zr[5]+=zr[7]; zi[5]+=zi[7]; zr[7]=-ti; zi[7]=tr;
  tr = zr[0]-zr[1]; ti = zi[0]-zi[1]; zr[0]+=zr[1]; zi[0]+=zi[1]; zr[1]=tr; zi[1]=ti;
  tr = zr[2]-zr[3]; ti = zi[2]-zi[3]; zr[2]+=zr[3]; zi[2]+=zi[3]; zr[3]=tr; zi[3]=ti;
  tr = zr[4]-zr[5]; ti = zi[4]-zi[5]; zr[4]+=zr[5]; zi[4]+=zi[5]; zr[5]=tr; zi[5]=ti;
  tr = zr[6]-zr[7]; ti = zi[6]-zi[7]; zr[6]+=zr[7]; zi[6]+=zi[7]; zr[7]=tr; zi[7]=ti;
}

__global__ __launch_bounds__(1024, 8) void k_fused(
    const float* __restrict__ sre, const float* __restrict__ sim,
    const float* __restrict__ win, float* __restrict__ out) {
  __shared__ __align__(16) float2 lds2[LDS2N];
  float2* S    = lds2;                 // 16 frame rows, stride FS2
  float2* PRE2 = lds2 + PREOFF;        // e^{+i pi k/512}, k=0..511
  float2* WIN2 = lds2 + WINOFF;        // (win[2m], win[2m+1]) * 0.5/512

  const int t   = threadIdx.x;
  const int b   = blockIdx.x & 15;
  const int wgq = blockIdx.x >> 4;
  const int f_base = HPW * wgq - 2;    // even
  const int s0     = SPW * wgq;
  const int w  = t >> 6;               // wave id = frame slot
  const int j  = t & 63;               // lane = butterfly index

  // ---- stage spectra: coalesced float2 global loads -> frame-major rows ----
  {
    const float2* __restrict__ sre2 = (const float2*)sre + (size_t)b * (FREQ_ * 1024);
    const float2* __restrict__ sim2 = (const float2*)sim + (size_t)b * (FREQ_ * 1024);
    const int wp  = t & 7;                       // frame-pair slot
    const int fg0 = f_base + (wp << 1);          // even; validity pair-aligned
    const bool pv = (fg0 >= 0) && (fg0 < FRAMES_);
    const int cb2 = (pv ? fg0 : 0) >> 1;         // safe float2 col
    const int row0 = t >> 3;
#pragma unroll
    for (int k = 0; k < 4; ++k) {
      const int row = row0 + (k << 7);           // 0..511
      const int a   = (row << 10) + cb2;
      float2 re2 = sre2[a];
      float2 im2 = sim2[a];
      if (!pv) { re2 = make_float2(0.f, 0.f); im2 = make_float2(0.f, 0.f); }
      S[(wp << 1) * FS2 + row]       = make_float2(re2.x, im2.x);
      S[((wp << 1) + 1) * FS2 + row] = make_float2(re2.y, im2.y);
    }
    if (t < 8) {                                 // row 512 tail
      const int a = (512 << 10) + cb2;
      float2 re2 = sre2[a];
      float2 im2 = sim2[a];
      if (!pv) { re2 = make_float2(0.f, 0.f); im2 = make_float2(0.f, 0.f); }
      S[(wp << 1) * FS2 + 512]       = make_float2(re2.x, im2.x);
      S[((wp << 1) + 1) * FS2 + 512] = make_float2(re2.y, im2.y);
    }
  }

  // ---- pass-1 twiddles in registers: tw1[p] = W_512^{j*p} = e^{+2pi i j p/512}
  // (1 sincos + 6 cmuls; hidden under staging-load latency)
  float2 tw1[8];
  {
    float s_, c_;
    __sincosf((float)j * (6.2831853071795864769f / 512.f), &s_, &c_);
    tw1[1] = make_float2(c_, s_);
#pragma unroll
    for (int p = 2; p < 8; ++p) tw1[p] = cmul(tw1[p - 1], tw1[1]);
  }

  // ---- tables (overlapped with staging-load latency) ----
  if (t < 512) {
    float s_, c_;
    __sincosf((float)t * (3.1415926535897932385f / 512.f), &s_, &c_);
    PRE2[t] = make_float2(c_, s_);
    const float2 wv = ((const float2*)win)[t];
    WIN2[t] = make_float2(wv.x * (0.5f / 512.0f), wv.y * (0.5f / 512.0f));
  }
  __syncthreads();                               // barrier A

  // ================= per-wave FFT (no barriers) =================
  float2* Zs = S + w * FS2;              // this wave's private row
  const int brev3[8] = {0, 4, 2, 6, 1, 5, 3, 7};

  // load + E/O fold (scale folded into WIN2; invalid frames are zero)
  float2 x1[8], x2[8];
#pragma unroll
  for (int m = 0; m < 8; ++m) {
    x1[m] = Zs[j + (m << 6)];
    x2[m] = Zs[512 - j - (m << 6)];
  }
  float zr[8], zi[8];
#pragma unroll
  for (int m = 0; m < 8; ++m) {
    const int i = j + (m << 6);
    float ar = x1[m].x, ai = x1[m].y;
    float br = x2[m].x, bi = x2[m].y;
    if (i == 0) { ai = 0.f; bi = 0.f; }  // irfft ignores Im of bins 0,512
    const float Er = ar + br, Ei = ai - bi;
    const float Dr = ar - br, Di = ai + bi;
    const float2 pw = PRE2[i];           // e^{+2pi i * i /1024}
    const float Or = pw.x * Dr - pw.y * Di;
    const float Oi = pw.x * Di + pw.y * Dr;
    zr[m] = Er - Oi;
    zi[m] = Ei + Or;
  }
  idft8(zr, zi);
  // pass 1 write (swizzle a = s ^ (s>>3); s = mp*64 + j), register twiddles
  const int jx = j ^ (j >> 3);
#pragma unroll
  for (int r = 0; r < 8; ++r) {
    const int mp = brev3[r];
    const int a  = (mp << 6) | (jx ^ (mp << 3));
    if (mp == 0) Zs[a] = make_float2(zr[r], zi[r]);
    else {
      const float2 tw = tw1[mp];         // W_512^{j*mp}
      Zs[a] = make_float2(zr[r]*tw.x - zi[r]*tw.y, zr[r]*tw.y + zi[r]*tw.x);
    }
  }
  // ---- pass-2 twiddles in registers: tw2[p] = W_64^{pos*p} ----
  const int pos = j & 7, blk = j >> 3;
  float2 tw2[8];
  {
    float s_, c_;
    __sincosf((float)pos * (6.2831853071795864769f / 64.f), &s_, &c_);
    tw2[1] = make_float2(c_, s_);
#pragma unroll
    for (int p = 2; p < 8; ++p) tw2[p] = cmul(tw2[p - 1], tw2[1]);
  }
  LGKM_SYNC();
  // pass 2 (s_read = blk*64 + m*8 + pos; s_write = blk*64 + mp*8 + pos)
  {
#pragma unroll
    for (int m = 0; m < 8; ++m) {
      const int a = (blk << 6) | (((m << 3) | pos) ^ ((blk << 3) | m));
      const float2 v = Zs[a];
      zr[m] = v.x; zi[m] = v.y;
    }
    idft8(zr, zi);
#pragma unroll
    for (int r = 0; r < 8; ++r) {
      const int mp = brev3[r];
      const int a  = (blk << 6) | (((mp << 3) | pos) ^ ((blk << 3) | mp));
      if (mp == 0) Zs[a] = make_float2(zr[r], zi[r]);
      else {
        const float2 tw = tw2[mp];       // W_64^{pos*mp}
        Zs[a] = make_float2(zr[r]*tw.x - zi[r]*tw.y, zr[r]*tw.y + zi[r]*tw.x);
      }
    }
  }
  LGKM_SYNC();
  // pass 3 (s = j*8 + m -> a = ((j<<3)^j) ^ m), final butterfly, twiddle-free
  float yr[8], yi[8];
  {
    const int b3 = (j << 3) ^ j;
#pragma unroll
    for (int m = 0; m < 8; ++m) {
      const float2 v = Zs[b3 ^ m];
      yr[m] = v.x; yi[m] = v.y;
    }
  }
  idft8(yr, yi);
  // window + overwrite own row as [even 512 | odd 512] floats, bank-swizzled
  // time sample pair mt: x[2mt]=Re z[mt], x[2mt+1]=Im z[mt]; mt = brev3(r)*64+c
  {
    const int c = ((j & 7) << 3) | (j >> 3);      // Stockham output perm
    float* XWrow = (float*)Zs;
#pragma unroll
    for (int r = 0; r < 8; ++r) {
      const int mp = brev3[r];
      const int mt = (mp << 6) | c;
      const int ms = SWZ(mt);
      const float2 wv = WIN2[mt];
      XWrow[ms]       = yr[r] * wv.x;
      XWrow[512 + ms] = yi[r] * wv.y;
    }
  }
  __syncthreads();                               // barrier B

  // ---- overlap-add + envelope divide + coalesced float2 store ----
  // COLA: sum_j hann^2(p+256j) = 1.5 exactly -> invenv = 2/3 except edges.
  float* __restrict__ outb = out + (size_t)b * T_OUT_;
  const float* ldsf = (const float*)lds2;
#pragma unroll
  for (int rr = 0; rr < 2; ++rr) {
    const int idx = t + (rr << 10);    // 0..1535 used
    if (idx < 1536) {
      const int s = s0 + (idx << 1);
      if (s < T_OUT_) {
        const int u   = s + PAD_;
        const int fh  = u >> 8;
        const int me0 = (u & 255) >> 1;     // even-sample index within hop
        float vr = 0.f, vi = 0.f;
#pragma unroll
        for (int jj = 0; jj < 4; ++jj) {
          const int fl = fh - jj - f_base;  // 0..15 by construction
          const int mt = (jj << 7) + me0;
          const int af = fl * (FS2 * 2) + SWZ(mt);
          vr += ldsf[af];
          vi += ldsf[af + 512];
        }
        float ivx, ivy;
        if (u >= 768 && u <= T_OUT_ - 2) {  // full-overlap interior
          ivx = 0.66666666667f; ivy = 0.66666666667f;
        } else {                            // edge samples only
          float iv[2];
#pragma unroll
          for (int h = 0; h < 2; ++h) {
            const int uu  = u + h;
            const int fh2 = min(FRAMES_ - 1, uu >> 8);
            const int fl2 = (uu >= 1024) ? (((uu - 1024) >> 8) + 1) : 0;
            float e = 0.f;
            for (int ff = fl2; ff <= fh2; ++ff) {
              const float ww = win[uu - (ff << 8)];
              e += ww * ww;
            }
            iv[h] = 1.0f / e;
          }
          ivx = iv[0]; ivy = iv[1];
        }
        *(float2*)(outb + s) = make_float2(vr * ivx, vi * ivy);
      }
    }
  }
}

extern "C" void kernel_launch(void* const* d_in, const int* in_sizes, int n_in,
                              void* d_out, int out_size, void* d_ws, size_t ws_size,
                              hipStream_t stream) {
  (void)in_sizes; (void)n_in; (void)out_size; (void)d_ws; (void)ws_size;
  const float* sre = (const float*)d_in[0];
  const float* sim = (const float*)d_in[1];
  const float* win = (const float*)d_in[2];
  float* out = (float*)d_out;
  k_fused<<<B_ * NCHUNK, 1024, 0, stream>>>(sre, sim, win, out);
}

// Round 5
// 183.884 us; speedup vs baseline: 1.1054x; 1.1054x over previous
//
#include <hip/hip_runtime.h>

// Fused Xcodec2 ISTFT: B=16, FREQ=513, FRAMES=2048, n_fft=1024, hop=256, win=1024
// out: [16, 1, 524288] fp32
//
// One-frame-per-wave version (barrier-free FFT), round 5:
//  - Spectra staged coalesced global -> frame-major LDS rows (float2 loads),
//    invalid frame-pairs zeroed at staging (validity is pair-aligned).
//  - Each wave runs one 512-pt complex inverse FFT (radix-8 Stockham, 3 reg
//    butterflies, 2 in-row LDS exchanges) in its own LDS row; wave-local
//    lgkmcnt fences only. Z slots XOR-swizzled (a = s ^ (s>>3)): conflict-free.
//  - Twiddles via RUNNING PRODUCT in registers (1 sincos + 1 cmul per store):
//    brev3 is an involution, so the write loop iterates mp=0..7 with
//    r=brev3[mp] and wacc *= W each step. Only 2 float2 of twiddle state live
//    (round 4's tw[8] arrays caused scratch spills: WRITE_SIZE 33->66 MB).
//  - Pass-1 LDS loads interleaved with the E/O fold (no x1/x2[8] arrays).
//  - Windowed frame written with SWZ(x)=x^((x&32)>>1) bank swizzle; OLA reads
//    apply the same swizzle.
//  - ifft scale (0.5/512) folded into the LDS window table.
//  - COLA: sum_j hann^2(p+256j) = 1.5 -> invenv = 2/3 except edges.
//  - 2 barriers total.

#define B_      16
#define FREQ_   513
#define FRAMES_ 2048
#define HOP_    256
#define NH_     512
#define PAD_    384
#define T_OUT_  524288
#define HPW     12           // useful hops per WG
#define SPW     3072         // output samples per WG
#define NCHUNK  171          // ceil(T_OUT/SPW)

#define FS2     515          // float2 stride of one frame row in S
#define PREOFF  8240         // float2 offset of PRE (16*515)
#define WINOFF  8752         // float2 offset of WIN
#define LDS2N   9264         // total float2 (74,112 B -> 2 WG/CU)

#define LGKM_SYNC() asm volatile("s_waitcnt lgkmcnt(0)" ::: "memory")
#define SWZ(x) ((x) ^ (((x) & 32) >> 1))

__device__ __forceinline__ float2 cmul(float2 a, float2 b) {
  return make_float2(a.x * b.x - a.y * b.y, a.x * b.y + a.y * b.x);
}

// 8-point inverse DFT (sign +i), DIF, in-place; output slot r holds y[brev3(r)].
__device__ __forceinline__ void idft8(float* zr, float* zi) {
  const float C = 0.70710678118654752f;
  float tr, ti;
  tr = zr[0]-zr[4]; ti = zi[0]-zi[4]; zr[0]+=zr[4]; zi[0]+=zi[4]; zr[4]=tr;         zi[4]=ti;
  tr = zr[1]-zr[5]; ti = zi[1]-zi[5]; zr[1]+=zr[5]; zi[1]+=zi[5]; zr[5]=C*(tr-ti);  zi[5]=C*(tr+ti);
  tr = zr[2]-zr[6]; ti = zi[2]-zi[6]; zr[2]+=zr[6]; zi[2]+=zi[6]; zr[6]=-ti;        zi[6]=tr;
  tr = zr[3]-zr[7]; ti = zi[3]-zi[7]; zr[3]+=zr[7]; zi[3]+=zi[7]; zr[7]=-C*(tr+ti); zi[7]=C*(tr-ti);
  tr = zr[0]-zr[2]; ti = zi[0]-zi[2]; zr[0]+=zr[2]; zi[0]+=zi[2]; zr[2]=tr;  zi[2]=ti;
  tr = zr[1]-zr[3]; ti = zi[1]-zi[3]; zr[1]+=zr[3]; zi[1]+=zi[3]; zr[3]=-ti; zi[3]=tr;
  tr = zr[4]-zr[6]; ti = zi[4]-zi[6]; zr[4]+=zr[6]; zi[4]+=zi[6]; zr[6]=tr;  zi[6]=ti;
  tr = zr[5]-zr[7]; ti = zi[5]-zi[7]; zr[5]+=zr[7]; zi[5]+=zi[7]; zr[7]=-ti; zi[7]=tr;
  tr = zr[0]-zr[1]; ti = zi[0]-zi[1]; zr[0]+=zr[1]; zi[0]+=zi[1]; zr[1]=tr; zi[1]=ti;
  tr = zr[2]-zr[3]; ti = zi[2]-zi[3]; zr[2]+=zr[3]; zi[2]+=zi[3]; zr[3]=tr; zi[3]=ti;
  tr = zr[4]-zr[5]; ti = zi[4]-zi[5]; zr[4]+=zr[5]; zi[4]+=zi[5]; zr[5]=tr; zi[5]=ti;
  tr = zr[6]-zr[7]; ti = zi[6]-zi[7]; zr[6]+=zr[7]; zi[6]+=zi[7]; zr[7]=tr; zi[7]=ti;
}

__global__ __launch_bounds__(1024, 8) void k_fused(
    const float* __restrict__ sre, const float* __restrict__ sim,
    const float* __restrict__ win, float* __restrict__ out) {
  __shared__ __align__(16) float2 lds2[LDS2N];
  float2* S    = lds2;                 // 16 frame rows, stride FS2
  float2* PRE2 = lds2 + PREOFF;        // e^{+i pi k/512}, k=0..511
  float2* WIN2 = lds2 + WINOFF;        // (win[2m], win[2m+1]) * 0.5/512

  const int t   = threadIdx.x;
  const int b   = blockIdx.x & 15;
  const int wgq = blockIdx.x >> 4;
  const int f_base = HPW * wgq - 2;    // even
  const int s0     = SPW * wgq;
  const int w  = t >> 6;               // wave id = frame slot
  const int j  = t & 63;               // lane = butterfly index

  // ---- stage spectra: coalesced float2 global loads -> frame-major rows ----
  {
    const float2* __restrict__ sre2 = (const float2*)sre + (size_t)b * (FREQ_ * 1024);
    const float2* __restrict__ sim2 = (const float2*)sim + (size_t)b * (FREQ_ * 1024);
    const int wp  = t & 7;                       // frame-pair slot
    const int fg0 = f_base + (wp << 1);          // even; validity pair-aligned
    const bool pv = (fg0 >= 0) && (fg0 < FRAMES_);
    const int cb2 = (pv ? fg0 : 0) >> 1;         // safe float2 col
    const int row0 = t >> 3;
#pragma unroll
    for (int k = 0; k < 4; ++k) {
      const int row = row0 + (k << 7);           // 0..511
      const int a   = (row << 10) + cb2;
      float2 re2 = sre2[a];
      float2 im2 = sim2[a];
      if (!pv) { re2 = make_float2(0.f, 0.f); im2 = make_float2(0.f, 0.f); }
      S[(wp << 1) * FS2 + row]       = make_float2(re2.x, im2.x);
      S[((wp << 1) + 1) * FS2 + row] = make_float2(re2.y, im2.y);
    }
    if (t < 8) {                                 // row 512 tail
      const int a = (512 << 10) + cb2;
      float2 re2 = sre2[a];
      float2 im2 = sim2[a];
      if (!pv) { re2 = make_float2(0.f, 0.f); im2 = make_float2(0.f, 0.f); }
      S[(wp << 1) * FS2 + 512]       = make_float2(re2.x, im2.x);
      S[((wp << 1) + 1) * FS2 + 512] = make_float2(re2.y, im2.y);
    }
  }

  // base twiddles (1 sincos each; hidden under staging-load latency)
  float2 tw1b, tw2b;
  {
    float s_, c_;
    __sincosf((float)j * (6.2831853071795864769f / 512.f), &s_, &c_);
    tw1b = make_float2(c_, s_);                  // W_512^j
    __sincosf((float)(j & 7) * (6.2831853071795864769f / 64.f), &s_, &c_);
    tw2b = make_float2(c_, s_);                  // W_64^pos
  }

  // ---- tables (overlapped with staging-load latency) ----
  if (t < 512) {
    float s_, c_;
    __sincosf((float)t * (3.1415926535897932385f / 512.f), &s_, &c_);
    PRE2[t] = make_float2(c_, s_);
    const float2 wv = ((const float2*)win)[t];
    WIN2[t] = make_float2(wv.x * (0.5f / 512.0f), wv.y * (0.5f / 512.0f));
  }
  __syncthreads();                               // barrier A

  // ================= per-wave FFT (no barriers) =================
  float2* Zs = S + w * FS2;              // this wave's private row
  const int brev3[8] = {0, 4, 2, 6, 1, 5, 3, 7};

  // pass 1 load + E/O fold, interleaved (low register pressure)
  float zr[8], zi[8];
#pragma unroll
  for (int m = 0; m < 8; ++m) {
    const int i = j + (m << 6);
    const float2 xa = Zs[i];
    const float2 xb = Zs[512 - i];
    float ar = xa.x, ai = xa.y;
    float br = xb.x, bi = xb.y;
    if (i == 0) { ai = 0.f; bi = 0.f; }  // irfft ignores Im of bins 0,512
    const float Er = ar + br, Ei = ai - bi;
    const float Dr = ar - br, Di = ai + bi;
    const float2 pw = PRE2[i];           // e^{+2pi i * i /1024}
    const float Or = pw.x * Dr - pw.y * Di;
    const float Oi = pw.x * Di + pw.y * Dr;
    zr[m] = Er - Oi;
    zi[m] = Ei + Or;
  }
  idft8(zr, zi);
  // pass 1 write in mp order (r = brev3[mp], involution) with running twiddle
  {
    const int jx = j ^ (j >> 3);
    float2 wacc = tw1b;                  // W_512^{j*1}
#pragma unroll
    for (int mp = 0; mp < 8; ++mp) {
      const int r = brev3[mp];
      const int a = (mp << 6) | (jx ^ (mp << 3));
      if (mp == 0) Zs[a] = make_float2(zr[r], zi[r]);
      else {
        Zs[a] = make_float2(zr[r]*wacc.x - zi[r]*wacc.y,
                            zr[r]*wacc.y + zi[r]*wacc.x);
        wacc = cmul(wacc, tw1b);
      }
    }
  }
  LGKM_SYNC();
  // pass 2 (s_read = blk*64 + m*8 + pos; s_write = blk*64 + mp*8 + pos)
  const int pos = j & 7, blk = j >> 3;
  {
#pragma unroll
    for (int m = 0; m < 8; ++m) {
      const int a = (blk << 6) | (((m << 3) | pos) ^ ((blk << 3) | m));
      const float2 v = Zs[a];
      zr[m] = v.x; zi[m] = v.y;
    }
    idft8(zr, zi);
    float2 wacc = tw2b;                  // W_64^{pos*1}
#pragma unroll
    for (int mp = 0; mp < 8; ++mp) {
      const int r = brev3[mp];
      const int a = (blk << 6) | (((mp << 3) | pos) ^ ((blk << 3) | mp));
      if (mp == 0) Zs[a] = make_float2(zr[r], zi[r]);
      else {
        Zs[a] = make_float2(zr[r]*wacc.x - zi[r]*wacc.y,
                            zr[r]*wacc.y + zi[r]*wacc.x);
        wacc = cmul(wacc, tw2b);
      }
    }
  }
  LGKM_SYNC();
  // pass 3 (s = j*8 + m -> a = ((j<<3)^j) ^ m), final butterfly, twiddle-free
  float yr[8], yi[8];
  {
    const int b3 = (j << 3) ^ j;
#pragma unroll
    for (int m = 0; m < 8; ++m) {
      const float2 v = Zs[b3 ^ m];
      yr[m] = v.x; yi[m] = v.y;
    }
  }
  idft8(yr, yi);
  // window + overwrite own row as [even 512 | odd 512] floats, bank-swizzled
  // time sample pair mt: x[2mt]=Re z[mt], x[2mt+1]=Im z[mt]; mt = brev3(r)*64+c
  {
    const int c = ((j & 7) << 3) | (j >> 3);      // Stockham output perm
    float* XWrow = (float*)Zs;
#pragma unroll
    for (int r = 0; r < 8; ++r) {
      const int mp = brev3[r];
      const int mt = (mp << 6) | c;
      const int ms = SWZ(mt);
      const float2 wv = WIN2[mt];
      XWrow[ms]       = yr[r] * wv.x;
      XWrow[512 + ms] = yi[r] * wv.y;
    }
  }
  __syncthreads();                               // barrier B

  // ---- overlap-add + envelope divide + coalesced float2 store ----
  // COLA: sum_j hann^2(p+256j) = 1.5 exactly -> invenv = 2/3 except edges.
  float* __restrict__ outb = out + (size_t)b * T_OUT_;
  const float* ldsf = (const float*)lds2;
#pragma unroll
  for (int rr = 0; rr < 2; ++rr) {
    const int idx = t + (rr << 10);    // 0..1535 used
    if (idx < 1536) {
      const int s = s0 + (idx << 1);
      if (s < T_OUT_) {
        const int u   = s + PAD_;
        const int fh  = u >> 8;
        const int me0 = (u & 255) >> 1;     // even-sample index within hop
        float vr = 0.f, vi = 0.f;
#pragma unroll
        for (int jj = 0; jj < 4; ++jj) {
          const int fl = fh - jj - f_base;  // 0..15 by construction
          const int mt = (jj << 7) + me0;
          const int af = fl * (FS2 * 2) + SWZ(mt);
          vr += ldsf[af];
          vi += ldsf[af + 512];
        }
        float ivx, ivy;
        if (u >= 768 && u <= T_OUT_ - 2) {  // full-overlap interior
          ivx = 0.66666666667f; ivy = 0.66666666667f;
        } else {                            // edge samples only
          float iv[2];
#pragma unroll
          for (int h = 0; h < 2; ++h) {
            const int uu  = u + h;
            const int fh2 = min(FRAMES_ - 1, uu >> 8);
            const int fl2 = (uu >= 1024) ? (((uu - 1024) >> 8) + 1) : 0;
            float e = 0.f;
            for (int ff = fl2; ff <= fh2; ++ff) {
              const float ww = win[uu - (ff << 8)];
              e += ww * ww;
            }
            iv[h] = 1.0f / e;
          }
          ivx = iv[0]; ivy = iv[1];
        }
        *(float2*)(outb + s) = make_float2(vr * ivx, vi * ivy);
      }
    }
  }
}

extern "C" void kernel_launch(void* const* d_in, const int* in_sizes, int n_in,
                              void* d_out, int out_size, void* d_ws, size_t ws_size,
                              hipStream_t stream) {
  (void)in_sizes; (void)n_in; (void)out_size; (void)d_ws; (void)ws_size;
  const float* sre = (const float*)d_in[0];
  const float* sim = (const float*)d_in[1];
  const float* win = (const float*)d_in[2];
  float* out = (float*)d_out;
  k_fused<<<B_ * NCHUNK, 1024, 0, stream>>>(sre, sim, win, out);
}

// Round 6
// 180.961 us; speedup vs baseline: 1.1232x; 1.0162x over previous
//
#include <hip/hip_runtime.h>

// Fused Xcodec2 ISTFT: B=16, FREQ=513, FRAMES=2048, n_fft=1024, hop=256, win=1024
// out: [16, 1, 524288] fp32
//
// One-frame-per-wave version, round 6: packed-fp32 FFT core.
//  - Complex values held as ext_vector float2 (v2f) so clang emits
//    v_pk_add_f32 / v_pk_fma_f32 for the butterflies, E/O fold, cmul and
//    window multiply (~30% VALU-instruction cut vs scalar).
//  - Spectra staged coalesced global -> frame-major LDS rows, invalid
//    frame-pairs zeroed at staging (validity is pair-aligned).
//  - Per-wave 512-pt radix-8 Stockham FFT in the wave's own LDS row;
//    wave-local lgkmcnt fences only; Z slots XOR-swizzled (a = s ^ (s>>3)).
//  - Twiddles via running product in registers (2 float2 live; tw[8] arrays
//    spilled in round 4: WRITE_SIZE 33->66 MB).
//  - Windowed frame written with SWZ(x)=x^((x&32)>>1) bank swizzle; OLA reads
//    apply the same swizzle (stride-1 per lane -> conflict-free).
//  - Window table folds 0.5/512 (ifft norm+E/O) AND 2/3 (COLA interior
//    envelope): interior OLA store is a raw sum; edges multiply by 1.5/e.
//  - 2 barriers total.

#define B_      16
#define FREQ_   513
#define FRAMES_ 2048
#define HOP_    256
#define PAD_    384
#define T_OUT_  524288
#define HPW     12           // useful hops per WG
#define SPW     3072         // output samples per WG
#define NCHUNK  171          // ceil(T_OUT/SPW)

#define FS2     515          // v2f stride of one frame row in S
#define PREOFF  8240         // v2f offset of PRE (16*515)
#define WINOFF  8752         // v2f offset of WIN
#define LDS2N   9264         // total v2f (74,112 B -> 2 WG/CU)

#define LGKM_SYNC() asm volatile("s_waitcnt lgkmcnt(0)" ::: "memory")
#define SWZ(x) ((x) ^ (((x) & 32) >> 1))

typedef float v2f __attribute__((ext_vector_type(2)));

__device__ __forceinline__ v2f mk2(float a, float b) { v2f r; r.x = a; r.y = b; return r; }
// a*b complex; packs to 2 VOP3P ops (re-broadcast * b  +  im-broadcast * (-b.y, b.x))
__device__ __forceinline__ v2f cmul(v2f a, v2f b) {
  v2f re = mk2(a.x, a.x);
  v2f im = mk2(a.y, a.y);
  v2f bs = mk2(-b.y, b.x);
  return re * b + im * bs;
}
__device__ __forceinline__ v2f muli(v2f a) { return mk2(-a.y, a.x); }  // *(+i)

// 8-point inverse DFT (sign +i), DIF, in-place; output slot r holds y[brev3(r)].
// All add/sub butterflies are v2f -> packed fp32.
__device__ __forceinline__ void idft8(v2f* z) {
  const float C = 0.70710678118654752f;
  v2f t;
  t = z[0]-z[4]; z[0]+=z[4]; z[4]=t;
  t = z[1]-z[5]; z[1]+=z[5]; z[5]=mk2(C*(t.x-t.y), C*(t.x+t.y));
  t = z[2]-z[6]; z[2]+=z[6]; z[6]=muli(t);
  t = z[3]-z[7]; z[3]+=z[7]; z[7]=mk2(-C*(t.x+t.y), C*(t.x-t.y));
  t = z[0]-z[2]; z[0]+=z[2]; z[2]=t;
  t = z[1]-z[3]; z[1]+=z[3]; z[3]=muli(t);
  t = z[4]-z[6]; z[4]+=z[6]; z[6]=t;
  t = z[5]-z[7]; z[5]+=z[7]; z[7]=muli(t);
  t = z[0]-z[1]; z[0]+=z[1]; z[1]=t;
  t = z[2]-z[3]; z[2]+=z[3]; z[3]=t;
  t = z[4]-z[5]; z[4]+=z[5]; z[5]=t;
  t = z[6]-z[7]; z[6]+=z[7]; z[7]=t;
}

__global__ __launch_bounds__(1024, 8) void k_fused(
    const float* __restrict__ sre, const float* __restrict__ sim,
    const float* __restrict__ win, float* __restrict__ out) {
  __shared__ __align__(16) v2f lds2[LDS2N];
  v2f* S    = lds2;                 // 16 frame rows, stride FS2
  v2f* PRE2 = lds2 + PREOFF;        // e^{+i pi k/512}, k=0..511
  v2f* WIN2 = lds2 + WINOFF;        // (win[2m], win[2m+1]) * 0.5/512 * 2/3

  const int t   = threadIdx.x;
  const int b   = blockIdx.x & 15;
  const int wgq = blockIdx.x >> 4;
  const int f_base = HPW * wgq - 2;    // even
  const int s0     = SPW * wgq;
  const int w  = t >> 6;               // wave id = frame slot
  const int j  = t & 63;               // lane = butterfly index

  // ---- stage spectra: coalesced v2f global loads -> frame-major rows ----
  {
    const v2f* __restrict__ sre2 = (const v2f*)sre + (size_t)b * (FREQ_ * 1024);
    const v2f* __restrict__ sim2 = (const v2f*)sim + (size_t)b * (FREQ_ * 1024);
    const int wp  = t & 7;                       // frame-pair slot
    const int fg0 = f_base + (wp << 1);          // even; validity pair-aligned
    const bool pv = (fg0 >= 0) && (fg0 < FRAMES_);
    const int cb2 = (pv ? fg0 : 0) >> 1;         // safe v2f col
    const int row0 = t >> 3;
#pragma unroll
    for (int k = 0; k < 4; ++k) {
      const int row = row0 + (k << 7);           // 0..511
      const int a   = (row << 10) + cb2;
      v2f re2 = sre2[a];
      v2f im2 = sim2[a];
      if (!pv) { re2 = mk2(0.f, 0.f); im2 = mk2(0.f, 0.f); }
      S[(wp << 1) * FS2 + row]       = mk2(re2.x, im2.x);
      S[((wp << 1) + 1) * FS2 + row] = mk2(re2.y, im2.y);
    }
    if (t < 8) {                                 // row 512 tail
      const int a = (512 << 10) + cb2;
      v2f re2 = sre2[a];
      v2f im2 = sim2[a];
      if (!pv) { re2 = mk2(0.f, 0.f); im2 = mk2(0.f, 0.f); }
      S[(wp << 1) * FS2 + 512]       = mk2(re2.x, im2.x);
      S[((wp << 1) + 1) * FS2 + 512] = mk2(re2.y, im2.y);
    }
  }

  // base twiddles (1 sincos each; hidden under staging-load latency)
  v2f tw1b, tw2b;
  {
    float s_, c_;
    __sincosf((float)j * (6.2831853071795864769f / 512.f), &s_, &c_);
    tw1b = mk2(c_, s_);                  // W_512^j
    __sincosf((float)(j & 7) * (6.2831853071795864769f / 64.f), &s_, &c_);
    tw2b = mk2(c_, s_);                  // W_64^pos
  }

  // ---- tables (overlapped with staging-load latency) ----
  if (t < 512) {
    float s_, c_;
    __sincosf((float)t * (3.1415926535897932385f / 512.f), &s_, &c_);
    PRE2[t] = mk2(c_, s_);
    const v2f wv = ((const v2f*)win)[t];
    const float kk = (0.5f / 512.0f) * 0.66666666666666667f;
    WIN2[t] = mk2(wv.x * kk, wv.y * kk);
  }
  __syncthreads();                               // barrier A

  // ================= per-wave FFT (no barriers) =================
  v2f* Zs = S + w * FS2;                 // this wave's private row
  const int brev3[8] = {0, 4, 2, 6, 1, 5, 3, 7};

  // pass 1 load + E/O fold, interleaved (low register pressure, packed math)
  v2f z[8];
#pragma unroll
  for (int m = 0; m < 8; ++m) {
    const int i = j + (m << 6);
    v2f xa = Zs[i];
    v2f xb = Zs[512 - i];
    if (i == 0) { xa.y = 0.f; xb.y = 0.f; } // irfft ignores Im of bins 0,512
    const v2f bc = mk2(xb.x, -xb.y);        // conj(b)
    const v2f E  = xa + bc;                 // (ar+br, ai-bi)
    const v2f D  = xa - bc;                 // (ar-br, ai+bi)
    const v2f O  = cmul(PRE2[i], D);        // e^{+2pi i * i /1024} * D
    z[m] = E + muli(O);                     // (Er - Oi, Ei + Or)
  }
  idft8(z);
  // pass 1 write in mp order (r = brev3[mp], involution) with running twiddle
  {
    const int jx = j ^ (j >> 3);
    v2f wacc = tw1b;                     // W_512^{j*1}
#pragma unroll
    for (int mp = 0; mp < 8; ++mp) {
      const int r = brev3[mp];
      const int a = (mp << 6) | (jx ^ (mp << 3));
      if (mp == 0) Zs[a] = z[r];
      else {
        Zs[a] = cmul(z[r], wacc);
        wacc = cmul(wacc, tw1b);
      }
    }
  }
  LGKM_SYNC();
  // pass 2 (s_read = blk*64 + m*8 + pos; s_write = blk*64 + mp*8 + pos)
  const int pos = j & 7, blk = j >> 3;
  {
#pragma unroll
    for (int m = 0; m < 8; ++m) {
      const int a = (blk << 6) | (((m << 3) | pos) ^ ((blk << 3) | m));
      z[m] = Zs[a];
    }
    idft8(z);
    v2f wacc = tw2b;                     // W_64^{pos*1}
#pragma unroll
    for (int mp = 0; mp < 8; ++mp) {
      const int r = brev3[mp];
      const int a = (blk << 6) | (((mp << 3) | pos) ^ ((blk << 3) | mp));
      if (mp == 0) Zs[a] = z[r];
      else {
        Zs[a] = cmul(z[r], wacc);
        wacc = cmul(wacc, tw2b);
      }
    }
  }
  LGKM_SYNC();
  // pass 3 (s = j*8 + m -> a = ((j<<3)^j) ^ m), final butterfly, twiddle-free
  v2f y[8];
  {
    const int b3 = (j << 3) ^ j;
#pragma unroll
    for (int m = 0; m < 8; ++m) y[m] = Zs[b3 ^ m];
  }
  idft8(y);
  // window (packed mul) + overwrite own row as [even 512 | odd 512] floats,
  // bank-swizzled. pair mt: x[2mt]=Re z[mt], x[2mt+1]=Im z[mt]; mt=brev3(r)*64+c
  {
    const int c = ((j & 7) << 3) | (j >> 3);      // Stockham output perm
    float* XWrow = (float*)Zs;
#pragma unroll
    for (int r = 0; r < 8; ++r) {
      const int mp = brev3[r];
      const int mt = (mp << 6) | c;
      const int ms = SWZ(mt);
      const v2f p  = y[r] * WIN2[mt];             // packed window multiply
      XWrow[ms]       = p.x;
      XWrow[512 + ms] = p.y;
    }
  }
  __syncthreads();                               // barrier B

  // ---- overlap-add + envelope divide + coalesced v2f store ----
  // WIN2 already folds the interior 2/3; edges multiply by 1.5/e.
  float* __restrict__ outb = out + (size_t)b * T_OUT_;
  const float* ldsf = (const float*)lds2;
#pragma unroll
  for (int rr = 0; rr < 2; ++rr) {
    const int idx = t + (rr << 10);    // 0..1535 used
    if (idx < 1536) {
      const int s = s0 + (idx << 1);
      if (s < T_OUT_) {
        const int u   = s + PAD_;
        const int fh  = u >> 8;
        const int me0 = (u & 255) >> 1;     // even-sample index within hop
        float vr = 0.f, vi = 0.f;
#pragma unroll
        for (int jj = 0; jj < 4; ++jj) {
          const int fl = fh - jj - f_base;  // 0..15 by construction
          const int mt = (jj << 7) + me0;
          const int af = fl * (FS2 * 2) + SWZ(mt);
          vr += ldsf[af];
          vi += ldsf[af + 512];
        }
        v2f o;
        if (u >= 768 && u <= T_OUT_ - 2) {  // full-overlap interior
          o = mk2(vr, vi);
        } else {                            // edge samples only
          float iv[2];
#pragma unroll
          for (int h = 0; h < 2; ++h) {
            const int uu  = u + h;
            const int fh2 = min(FRAMES_ - 1, uu >> 8);
            const int fl2 = (uu >= 1024) ? (((uu - 1024) >> 8) + 1) : 0;
            float e = 0.f;
            for (int ff = fl2; ff <= fh2; ++ff) {
              const float ww = win[uu - (ff << 8)];
              e += ww * ww;
            }
            iv[h] = 1.5f / e;               // 1.5 compensates folded 2/3
          }
          o = mk2(vr * iv[0], vi * iv[1]);
        }
        *(v2f*)(outb + s) = o;
      }
    }
  }
}

extern "C" void kernel_launch(void* const* d_in, const int* in_sizes, int n_in,
                              void* d_out, int out_size, void* d_ws, size_t ws_size,
                              hipStream_t stream) {
  (void)in_sizes; (void)n_in; (void)out_size; (void)d_ws; (void)ws_size;
  const float* sre = (const float*)d_in[0];
  const float* sim = (const float*)d_in[1];
  const float* win = (const float*)d_in[2];
  float* out = (float*)d_out;
  k_fused<<<B_ * NCHUNK, 1024, 0, stream>>>(sre, sim, win, out);
}